// Round 4
// baseline (502.372 us; speedup 1.0000x reference)
//
#include <hip/hip_runtime.h>
#include <hip/hip_bf16.h>

#define NWIN 256
#define NV 343
#define VPAD 352
#define NTOK (NWIN * NV)          // 87808
#define NC 96
#define NH 3
#define HD 32
#define NQKV 288                  // 3*96
#define NTABLE 2197
#define SCALE_Q 0.17677669529663687f

typedef __attribute__((ext_vector_type(8))) short bf16x8;
typedef __attribute__((ext_vector_type(4))) float f32x4;

static __device__ __forceinline__ unsigned short f2b(float f) {
    union { __hip_bfloat16 b; unsigned short u; } cv;
    cv.b = __float2bfloat16(f);
    return cv.u;
}
static __device__ __forceinline__ float b2f(unsigned short u) {
    union { unsigned short u; __hip_bfloat16 b; } cv;
    cv.u = u;
    return __bfloat162float(cv.b);
}
static __device__ __forceinline__ f32x4 mfma16(bf16x8 a, bf16x8 b, f32x4 c) {
    return __builtin_amdgcn_mfma_f32_16x16x32_bf16(a, b, c, 0, 0, 0);
}

// ======================= workspace layout =======================
#define WS_WBF_OFF 0                                   // [288][96] bf16 = 55296
#define WS_QKV_OFF 65536                               // [87808][288] bf16 = 50577408
#define WS_NEEDED  (WS_QKV_OFF + (size_t)NTOK * NQKV * 2)

// ======================= kernel 0: W -> bf16 (scale folded) ====
__global__ __launch_bounds__(256) void wcvt(const float* __restrict__ w,
                                            unsigned short* __restrict__ wbf) {
    int i = blockIdx.x * 256 + threadIdx.x;           // 288*96 = 27648 exact
    float v = w[i];
    if (i < 96 * 96) v *= SCALE_Q;
    wbf[i] = f2b(v);
}

// ======================= kernel 1: qkv projection ==============
// grid 1372 x 256: block = 64 tokens, wave = 16 tokens x 288 cols. No LDS.
__global__ __launch_bounds__(256, 4) void proj(const float* __restrict__ x,
                                               const unsigned short* __restrict__ wbf,
                                               unsigned short* __restrict__ qkv) {
    const int lane = threadIdx.x & 63;
    const int wv = threadIdx.x >> 6;
    const int l15 = lane & 15;
    const int l4 = lane >> 4;
    const int r0 = blockIdx.x * 64 + wv * 16;         // r0+15 <= 87807 exact
    const int r = r0 + l15;

    bf16x8 a[3];
    #pragma unroll
    for (int ks = 0; ks < 3; ++ks) {
        const float* xp = x + (size_t)r * NC + ks * 32 + l4 * 8;
        float4 x0 = *(const float4*)xp;
        float4 x1 = *(const float4*)(xp + 4);
        bf16x8 t;
        t[0] = (short)f2b(x0.x); t[1] = (short)f2b(x0.y);
        t[2] = (short)f2b(x0.z); t[3] = (short)f2b(x0.w);
        t[4] = (short)f2b(x1.x); t[5] = (short)f2b(x1.y);
        t[6] = (short)f2b(x1.z); t[7] = (short)f2b(x1.w);
        a[ks] = t;
    }
    #pragma unroll
    for (int nt = 0; nt < 18; ++nt) {
        f32x4 acc = {0.f, 0.f, 0.f, 0.f};
        #pragma unroll
        for (int ks = 0; ks < 3; ++ks) {
            bf16x8 b = *(const bf16x8*)(wbf + (nt * 16 + l15) * NC + ks * 32 + l4 * 8);
            acc = mfma16(a[ks], b, acc);
        }
        int c = nt * 16 + l15;
        #pragma unroll
        for (int j = 0; j < 4; ++j)
            qkv[(size_t)(r0 + l4 * 4 + j) * NQKV + c] = f2b(acc[j]);
    }
}

// ======================= kernel 2: attention ===================
// LDS: v_t swz [32][352] 22528 | p_s swz [64][192] 24576 | bias bf16 4400 | mcode 1376
#define A_OFF_VT 0
#define A_OFF_PS 22528
#define A_OFF_B  47104
#define A_OFF_MC 51504
#define A_LDS    52880          // x3 blocks = 158640 <= 163840

static __device__ __forceinline__ int vt_addr(int ch, int tok) {
    int b = (ch * VPAD + tok) * 2;
    return A_OFF_VT + (b ^ ((ch & 7) << 4));
}
static __device__ __forceinline__ int ps_addr(int row, int col) {
    int b = (row * 192 + col) * 2;
    return A_OFF_PS + (b ^ ((row & 7) << 4));
}

__global__ __launch_bounds__(256, 3) void attn(const unsigned short* __restrict__ qkv,
                                               const float* __restrict__ mask,
                                               const float* __restrict__ bias_table,
                                               float* __restrict__ out) {
    __shared__ char lds[A_LDS];
    unsigned short* bias_l = (unsigned short*)(lds + A_OFF_B);
    int* mcode = (int*)(lds + A_OFF_MC);

    const int tid = threadIdx.x;
    const int lane = tid & 63;
    const int wv = tid >> 6;
    const int l15 = lane & 15;
    const int l4 = lane >> 4;

    int bid = blockIdx.x;
    int linear = (bid & 7) * 96 + (bid >> 3);   // 3 heads of a window -> same XCD
    int n = linear / 3;
    int h = linear - n * 3;

    for (int i = tid; i < NTABLE; i += 256) bias_l[i] = f2b(bias_table[h * NTABLE + i]);
    for (int i = tid; i < NV; i += 256) {
        int cz = i / 49; int rr = i - cz * 49; int cy = rr / 7; int cx = rr - cy * 7;
        mcode[i] = cz * 169 + cy * 13 + cx;     // rel_index(v,u) == mcode[v]-mcode[u]+1098
    }
    // stage V transposed (bf16, swizzled)
    const unsigned short* vrow = qkv + (size_t)n * NV * NQKV + 192 + h * HD;
    for (int i = tid; i < NV * 8; i += 256) {
        int tok = i >> 3, c4 = i & 7;
        ushort4 vv = *(const ushort4*)(vrow + (size_t)tok * NQKV + c4 * 4);
        *(unsigned short*)(lds + vt_addr(c4 * 4 + 0, tok)) = vv.x;
        *(unsigned short*)(lds + vt_addr(c4 * 4 + 1, tok)) = vv.y;
        *(unsigned short*)(lds + vt_addr(c4 * 4 + 2, tok)) = vv.z;
        *(unsigned short*)(lds + vt_addr(c4 * 4 + 3, tok)) = vv.w;
    }
    if (tid < 32 * 9) {                          // zero pad cols 343..351
        int ch = tid / 9, tok = NV + tid - ch * 9;
        *(unsigned short*)(lds + vt_addr(ch, tok)) = 0;
    }
    __syncthreads();

    const float* maskn = mask + (size_t)n * NV * NV;
    const unsigned short* qbase = qkv + (size_t)n * NV * NQKV + h * HD;
    const unsigned short* kbase = qbase + NC;

    for (int mc = 0; mc < 6; ++mc) {
        int r0 = mc * 64 + wv * 16;
        if (r0 >= VPAD) continue;                // no barriers below: divergence safe
        int t0 = r0 + l4 * 4;

        // mask prefetch
        float mk[22][4];
        #pragma unroll
        for (int t = 0; t < 22; ++t) {
            int u = t * 16 + l15;
            #pragma unroll
            for (int j = 0; j < 4; ++j) {
                int tok = t0 + j;
                mk[t][j] = (u < NV && tok < NV) ? maskn[(size_t)tok * NV + u] : 0.f;
            }
        }

        // QK^T: Q and K fragments straight from global (bf16 ws)
        int qr = min(r0 + l15, NV - 1);
        bf16x8 qa = *(const bf16x8*)(qbase + (size_t)qr * NQKV + l4 * 8);
        f32x4 p[22];
        #pragma unroll
        for (int t = 0; t < 22; ++t) {
            int u = min(t * 16 + l15, NV - 1);
            bf16x8 kb = *(const bf16x8*)(kbase + (size_t)u * NQKV + l4 * 8);
            f32x4 z = {0.f, 0.f, 0.f, 0.f};
            p[t] = mfma16(qa, kb, z);
        }

        int mv[4];
        #pragma unroll
        for (int j = 0; j < 4; ++j) {
            int tok = t0 + j;
            mv[j] = mcode[tok < NV ? tok : 0] + 1098;
        }
        float rmax[4] = {-1e30f, -1e30f, -1e30f, -1e30f};
        #pragma unroll
        for (int t = 0; t < 22; ++t) {
            int u = t * 16 + l15;
            bool uv = (u < NV);
            int mu = mcode[uv ? u : 0];
            #pragma unroll
            for (int j = 0; j < 4; ++j) {
                float val = p[t][j] + b2f(bias_l[mv[j] - mu]) + mk[t][j];
                val = uv ? val : -1e30f;
                p[t][j] = val;
                rmax[j] = fmaxf(rmax[j], val);
            }
        }
        #pragma unroll
        for (int m = 1; m < 16; m <<= 1) {
            #pragma unroll
            for (int j = 0; j < 4; ++j)
                rmax[j] = fmaxf(rmax[j], __shfl_xor(rmax[j], m, 64));
        }

        float rsum[4] = {0.f, 0.f, 0.f, 0.f};
        f32x4 o0 = {0.f, 0.f, 0.f, 0.f}, o1 = {0.f, 0.f, 0.f, 0.f};

        // ---- phase 1: tiles 0..11 -> p_s cols 0..191, AV over u 0..191
        #pragma unroll
        for (int t = 0; t < 12; ++t) {
            #pragma unroll
            for (int j = 0; j < 4; ++j) {
                float e = __expf(p[t][j] - rmax[j]);
                rsum[j] += e;
                *(unsigned short*)(lds + ps_addr(wv * 16 + l4 * 4 + j, t * 16 + l15)) = f2b(e);
            }
        }
        #pragma unroll
        for (int ks = 0; ks < 6; ++ks) {
            bf16x8 pa  = *(const bf16x8*)(lds + ps_addr(wv * 16 + l15, ks * 32 + l4 * 8));
            bf16x8 vb0 = *(const bf16x8*)(lds + vt_addr(l15, ks * 32 + l4 * 8));
            bf16x8 vb1 = *(const bf16x8*)(lds + vt_addr(16 + l15, ks * 32 + l4 * 8));
            o0 = mfma16(pa, vb0, o0);
            o1 = mfma16(pa, vb1, o1);
        }
        // ---- phase 2: tiles 12..21 -> p_s cols 0..159, AV over u 192..351
        #pragma unroll
        for (int t = 12; t < 22; ++t) {
            #pragma unroll
            for (int j = 0; j < 4; ++j) {
                float e = __expf(p[t][j] - rmax[j]);
                rsum[j] += e;
                *(unsigned short*)(lds + ps_addr(wv * 16 + l4 * 4 + j, (t - 12) * 16 + l15)) = f2b(e);
            }
        }
        #pragma unroll
        for (int ks = 0; ks < 5; ++ks) {
            bf16x8 pa  = *(const bf16x8*)(lds + ps_addr(wv * 16 + l15, ks * 32 + l4 * 8));
            bf16x8 vb0 = *(const bf16x8*)(lds + vt_addr(l15, 192 + ks * 32 + l4 * 8));
            bf16x8 vb1 = *(const bf16x8*)(lds + vt_addr(16 + l15, 192 + ks * 32 + l4 * 8));
            o0 = mfma16(pa, vb0, o0);
            o1 = mfma16(pa, vb1, o1);
        }

        #pragma unroll
        for (int m = 1; m < 16; m <<= 1) {
            #pragma unroll
            for (int j = 0; j < 4; ++j)
                rsum[j] += __shfl_xor(rsum[j], m, 64);
        }
        #pragma unroll
        for (int j = 0; j < 4; ++j) {
            int tok = t0 + j;
            if (tok < NV) {
                float inv = 1.0f / rsum[j];
                float* op = out + ((size_t)n * NV + tok) * NC + h * HD;
                op[l15]      = o0[j] * inv;
                op[16 + l15] = o1[j] * inv;
            }
        }
    }
}

// ======================= fallback: proven fused kernel =========
#define OFF_Q    0
#define OFF_K    22528
#define OFF_VT   45056
#define OFF_BIAS 67584
#define OFF_MC   76384
#define OFF_U    77760
#define OFF_XS   OFF_U
#define OFF_WS   (OFF_U + 13312)
#define OFF_PS   OFF_U
#define LDS_BYTES (OFF_U + 45056)

__global__ __launch_bounds__(256) void wattn(
    const float* __restrict__ x, const float* __restrict__ mask,
    const float* __restrict__ w_qkv, const float* __restrict__ bias_table,
    const int* __restrict__ rel_index, float* __restrict__ out)
{
    extern __shared__ char flds[];
    unsigned short* q_s  = (unsigned short*)(flds + OFF_Q);
    unsigned short* k_s  = (unsigned short*)(flds + OFF_K);
    unsigned short* v_t  = (unsigned short*)(flds + OFF_VT);
    float*          bias_l = (float*)(flds + OFF_BIAS);
    int*            mcode  = (int*)(flds + OFF_MC);
    unsigned short* xs   = (unsigned short*)(flds + OFF_XS);
    unsigned short* ws   = (unsigned short*)(flds + OFF_WS);
    unsigned short* p_s  = (unsigned short*)(flds + OFF_PS);

    const int tid = threadIdx.x;
    const int lane = tid & 63;
    const int wv  = tid >> 6;
    const int l15 = lane & 15;
    const int l4  = lane >> 4;

    int bid = blockIdx.x;
    int linear = (bid & 7) * 96 + (bid >> 3);
    int n = linear / 3;
    int h = linear - n * 3;

    for (int i = tid; i < NTABLE; i += 256) bias_l[i] = bias_table[h * NTABLE + i];
    for (int i = tid; i < NV; i += 256) {
        int cz = i / 49; int rr = i - cz * 49; int cy = rr / 7; int cx = rr - cy * 7;
        mcode[i] = cz * 169 + cy * 13 + cx;
    }
    for (int i = tid; i < 96 * 24; i += 256) {
        int nr = i / 24, c4 = i - nr * 24;
        int g = nr >> 5, d = nr & 31;
        const float4 wq = *(const float4*)(w_qkv + (size_t)(g * NC + h * HD + d) * NC + c4 * 4);
        float s = (g == 0) ? SCALE_Q : 1.0f;
        unsigned short* dst = ws + nr * 104 + c4 * 4;
        dst[0] = f2b(wq.x * s); dst[1] = f2b(wq.y * s);
        dst[2] = f2b(wq.z * s); dst[3] = f2b(wq.w * s);
    }
    for (int mc = 0; mc < 6; ++mc) {
        __syncthreads();
        for (int i = tid; i < 64 * 24; i += 256) {
            int r = i / 24, c4 = i - r * 24;
            int tok = mc * 64 + r;
            float4 xv = make_float4(0.f, 0.f, 0.f, 0.f);
            if (tok < NV) xv = *(const float4*)(x + ((size_t)n * NV + tok) * NC + c4 * 4);
            unsigned short* dst = xs + r * 104 + c4 * 4;
            dst[0] = f2b(xv.x); dst[1] = f2b(xv.y); dst[2] = f2b(xv.z); dst[3] = f2b(xv.w);
        }
        __syncthreads();
        int r0 = mc * 64 + wv * 16;
        if (r0 < VPAD) {
            bf16x8 a[3];
            #pragma unroll
            for (int ks = 0; ks < 3; ++ks)
                a[ks] = *(const bf16x8*)(xs + (wv * 16 + l15) * 104 + ks * 32 + l4 * 8);
            #pragma unroll
            for (int nt = 0; nt < 6; ++nt) {
                f32x4 acc = {0.f, 0.f, 0.f, 0.f};
                #pragma unroll
                for (int ks = 0; ks < 3; ++ks) {
                    bf16x8 b = *(const bf16x8*)(ws + (nt * 16 + l15) * 104 + ks * 32 + l4 * 8);
                    acc = mfma16(a[ks], b, acc);
                }
                int ch = (nt & 1) * 16 + l15;
                int t0 = r0 + l4 * 4;
                if (nt < 2) {
                    #pragma unroll
                    for (int j = 0; j < 4; ++j) q_s[(t0 + j) * 32 + ch] = f2b(acc[j]);
                } else if (nt < 4) {
                    #pragma unroll
                    for (int j = 0; j < 4; ++j) k_s[(t0 + j) * 32 + ch] = f2b(acc[j]);
                } else {
                    ushort4 pk;
                    pk.x = f2b(acc[0]); pk.y = f2b(acc[1]);
                    pk.z = f2b(acc[2]); pk.w = f2b(acc[3]);
                    *(ushort4*)(v_t + ch * VPAD + t0) = pk;
                }
            }
        }
    }
    __syncthreads();

    const float* maskn = mask + (size_t)n * NV * NV;
    for (int mc = 0; mc < 6; ++mc) {
        int r0 = mc * 64 + wv * 16;
        if (r0 >= VPAD) continue;
        int t0 = r0 + l4 * 4;
        float mk[22][4];
        #pragma unroll
        for (int t = 0; t < 22; ++t) {
            int u = t * 16 + l15;
            #pragma unroll
            for (int j = 0; j < 4; ++j) {
                int tok = t0 + j;
                mk[t][j] = (u < NV && tok < NV) ? maskn[(size_t)tok * NV + u] : 0.f;
            }
        }
        bf16x8 qa = *(const bf16x8*)(q_s + (r0 + l15) * 32 + l4 * 8);
        f32x4 p[22];
        #pragma unroll
        for (int t = 0; t < 22; ++t) {
            bf16x8 kb = *(const bf16x8*)(k_s + (t * 16 + l15) * 32 + l4 * 8);
            f32x4 z = {0.f, 0.f, 0.f, 0.f};
            p[t] = mfma16(qa, kb, z);
        }
        int mv[4];
        #pragma unroll
        for (int j = 0; j < 4; ++j) {
            int tok = t0 + j;
            mv[j] = mcode[tok < NV ? tok : 0] + 1098;
        }
        float rmax[4] = {-1e30f, -1e30f, -1e30f, -1e30f};
        #pragma unroll
        for (int t = 0; t < 22; ++t) {
            int u = t * 16 + l15;
            bool uv = (u < NV);
            int mu = mcode[uv ? u : 0];
            #pragma unroll
            for (int j = 0; j < 4; ++j) {
                float val = p[t][j] + bias_l[mv[j] - mu] + mk[t][j];
                val = uv ? val : -1e30f;
                p[t][j] = val;
                rmax[j] = fmaxf(rmax[j], val);
            }
        }
        #pragma unroll
        for (int m = 1; m < 16; m <<= 1) {
            #pragma unroll
            for (int j = 0; j < 4; ++j)
                rmax[j] = fmaxf(rmax[j], __shfl_xor(rmax[j], m, 64));
        }
        float rsum[4] = {0.f, 0.f, 0.f, 0.f};
        #pragma unroll
        for (int t = 0; t < 22; ++t) {
            #pragma unroll
            for (int j = 0; j < 4; ++j) {
                float e = __expf(p[t][j] - rmax[j]);
                rsum[j] += e;
                p_s[(wv * 16 + l4 * 4 + j) * VPAD + t * 16 + l15] = f2b(e);
            }
        }
        #pragma unroll
        for (int m = 1; m < 16; m <<= 1) {
            #pragma unroll
            for (int j = 0; j < 4; ++j)
                rsum[j] += __shfl_xor(rsum[j], m, 64);
        }
        f32x4 o0 = {0.f,0.f,0.f,0.f}, o1 = {0.f,0.f,0.f,0.f};
        #pragma unroll
        for (int ks = 0; ks < 11; ++ks) {
            bf16x8 pa  = *(const bf16x8*)(p_s + (wv * 16 + l15) * VPAD + ks * 32 + l4 * 8);
            bf16x8 vb0 = *(const bf16x8*)(v_t + l15 * VPAD + ks * 32 + l4 * 8);
            bf16x8 vb1 = *(const bf16x8*)(v_t + (16 + l15) * VPAD + ks * 32 + l4 * 8);
            o0 = mfma16(pa, vb0, o0);
            o1 = mfma16(pa, vb1, o1);
        }
        #pragma unroll
        for (int j = 0; j < 4; ++j) {
            int tok = t0 + j;
            if (tok < NV) {
                float inv = 1.0f / rsum[j];
                float* op = out + ((size_t)n * NV + tok) * NC + h * HD;
                op[l15]      = o0[j] * inv;
                op[16 + l15] = o1[j] * inv;
            }
        }
    }
}

extern "C" void kernel_launch(void* const* d_in, const int* in_sizes, int n_in,
                              void* d_out, int out_size, void* d_ws, size_t ws_size,
                              hipStream_t stream) {
    const float* x          = (const float*)d_in[0];
    const float* mask       = (const float*)d_in[1];
    const float* w_qkv      = (const float*)d_in[2];
    const float* bias_table = (const float*)d_in[3];
    const int*   rel_index  = (const int*)d_in[4];
    float* out = (float*)d_out;

    (void)rel_index; (void)in_sizes; (void)n_in; (void)out_size;

    if (ws_size >= WS_NEEDED) {
        unsigned short* wbf  = (unsigned short*)((char*)d_ws + WS_WBF_OFF);
        unsigned short* qkvb = (unsigned short*)((char*)d_ws + WS_QKV_OFF);
        wcvt<<<dim3(108), dim3(256), 0, stream>>>(w_qkv, wbf);
        proj<<<dim3(1372), dim3(256), 0, stream>>>(x, wbf, qkvb);
        attn<<<dim3(NWIN * NH), dim3(256), 0, stream>>>(qkvb, mask, bias_table, out);
    } else {
        hipFuncSetAttribute((const void*)wattn, hipFuncAttributeMaxDynamicSharedMemorySize, LDS_BYTES);
        wattn<<<dim3(NWIN * NH), dim3(256), LDS_BYTES, stream>>>(x, mask, w_qkv, bias_table, rel_index, out);
    }
}

// Round 7
// 344.923 us; speedup vs baseline: 1.4565x; 1.4565x over previous
//
#include <hip/hip_runtime.h>
#include <hip/hip_bf16.h>

#define NWIN 256
#define NV 343
#define NC 96
#define NH 3
#define NTABLE 2197
#define SCALE_Q 0.17677669529663687f

typedef __attribute__((ext_vector_type(8))) short bf16x8;
typedef __attribute__((ext_vector_type(4))) float f32x4;

static __device__ __forceinline__ unsigned short f2b(float f) {
    union { __hip_bfloat16 b; unsigned short u; } cv;
    cv.b = __float2bfloat16(f);
    return cv.u;
}
static __device__ __forceinline__ float b2f(unsigned short u) {
    union { unsigned short u; __hip_bfloat16 b; } cv;
    cv.u = u;
    return __bfloat162float(cv.b);
}
static __device__ __forceinline__ f32x4 mfma16(bf16x8 a, bf16x8 b, f32x4 c) {
    return __builtin_amdgcn_mfma_f32_16x16x32_bf16(a, b, c, 0, 0, 0);
}
static __device__ __forceinline__ bf16x8 ldx8(const float* p) {
    float4 x0 = *(const float4*)p;
    float4 x1 = *(const float4*)(p + 4);
    bf16x8 t;
    t[0] = (short)f2b(x0.x); t[1] = (short)f2b(x0.y);
    t[2] = (short)f2b(x0.z); t[3] = (short)f2b(x0.w);
    t[4] = (short)f2b(x1.x); t[5] = (short)f2b(x1.y);
    t[6] = (short)f2b(x1.z); t[7] = (short)f2b(x1.w);
    return t;
}

// ======================= workspace =======================
#define WS_NEEDED (288 * 96 * 2)

__global__ __launch_bounds__(256) void wcvt(const float* __restrict__ w,
                                            unsigned short* __restrict__ wbf) {
    int i = blockIdx.x * 256 + threadIdx.x;   // 288*96 = 27648 exact
    float v = w[i];
    if (i < 96 * 96) v *= SCALE_Q;
    wbf[i] = f2b(v);
}

// ======================= fused attention, 3 blocks/CU =======================
// LDS: k_s [352][32] bf16 swz | v_t [32][352] bf16 swz (704B rows) |
//      bias bf16 [2197] | mcode i16 [343] | q_buf/p_s union [64][32] bf16 swz
// Swizzle: byte ^ ((row&3)<<4) — bits 4-5 only; provably in-row bijective
// for 64B rows (c<64) and 704B rows (c=640+d, d<64 -> 640+(d^0x30)<=703).
#define AK_K   0
#define AK_V   22528
#define AK_B   45056
#define AK_MC  49456
#define AK_QP  50144
#define AK_LDS 54240   // x3 = 162720 <= 163840

__global__ __launch_bounds__(256, 3) void attn(
    const float* __restrict__ x, const float* __restrict__ mask,
    const unsigned short* __restrict__ wbf, const float* __restrict__ bias_table,
    float* __restrict__ out)
{
    __shared__ char lds[AK_LDS];
    unsigned short* bias_l = (unsigned short*)(lds + AK_B);
    short* mcode = (short*)(lds + AK_MC);

    const int tid = threadIdx.x;
    const int lane = tid & 63;
    const int wvv = tid >> 6;
    const int l15 = lane & 15;
    const int l4 = lane >> 4;

    int bid = blockIdx.x;
    int linear = (bid & 7) * 96 + (bid >> 3);   // 3 heads of a window -> same XCD
    int n = linear / 3;
    int h = linear - n * 3;

    for (int i = tid; i < NTABLE; i += 256) bias_l[i] = f2b(bias_table[h * NTABLE + i]);
    for (int i = tid; i < NV; i += 256) {
        int cz = i / 49; int rr = i - cz * 49; int cy = rr / 7; int cx = rr - cy * 7;
        mcode[i] = (short)(cz * 169 + cy * 13 + cx);  // rel_index(v,u)==mcode[v]-mcode[u]+1098
    }

    const unsigned short* wqp = wbf + (h * 32) * NC;
    const unsigned short* wkp = wbf + (96 + h * 32) * NC;
    const unsigned short* wvp = wbf + (192 + h * 32) * NC;
    const float* xn = x + (size_t)n * NV * NC;

#define BFRAG(WP, T, KS) (*(const bf16x8*)((WP) + ((T) * 16 + l15) * NC + (KS) * 32 + l4 * 8))

    // ---- phase A: K,V projection (A/B frags straight from global) ----
    #pragma unroll 1
    for (int mc = 0; mc < 6; ++mc) {
        int r0 = mc * 64 + wvv * 16;
        if (r0 >= 352) continue;
        int rr = min(r0 + l15, NV - 1);
        const float* xp = xn + (size_t)rr * NC + l4 * 8;   // per-lane k-chunk offset
        bf16x8 a0 = ldx8(xp), a1 = ldx8(xp + 32), a2 = ldx8(xp + 64);
        f32x4 k0 = {0.f,0.f,0.f,0.f}, k1 = {0.f,0.f,0.f,0.f};
        f32x4 v0 = {0.f,0.f,0.f,0.f}, v1 = {0.f,0.f,0.f,0.f};
        k0 = mfma16(a0, BFRAG(wkp,0,0), k0); k0 = mfma16(a1, BFRAG(wkp,0,1), k0); k0 = mfma16(a2, BFRAG(wkp,0,2), k0);
        k1 = mfma16(a0, BFRAG(wkp,1,0), k1); k1 = mfma16(a1, BFRAG(wkp,1,1), k1); k1 = mfma16(a2, BFRAG(wkp,1,2), k1);
        v0 = mfma16(a0, BFRAG(wvp,0,0), v0); v0 = mfma16(a1, BFRAG(wvp,0,1), v0); v0 = mfma16(a2, BFRAG(wvp,0,2), v0);
        v1 = mfma16(a0, BFRAG(wvp,1,0), v1); v1 = mfma16(a1, BFRAG(wvp,1,1), v1); v1 = mfma16(a2, BFRAG(wvp,1,2), v1);
        int t0 = r0 + l4 * 4;
        #pragma unroll
        for (int j = 0; j < 4; ++j) {
            int row = t0 + j;
            int sw = (row & 3) << 4;
            *(unsigned short*)(lds + AK_K + ((row * 64 + l15 * 2) ^ sw)) = f2b(k0[j]);
            *(unsigned short*)(lds + AK_K + ((row * 64 + 32 + l15 * 2) ^ sw)) = f2b(k1[j]);
        }
        {
            int vsw = (l15 & 3) << 4;
            ushort4 pk;
            pk.x = f2b(v0[0]); pk.y = f2b(v0[1]); pk.z = f2b(v0[2]); pk.w = f2b(v0[3]);
            *(ushort4*)(lds + AK_V + ((l15 * 704 + t0 * 2) ^ vsw)) = pk;
            ushort4 pk2;
            pk2.x = f2b(v1[0]); pk2.y = f2b(v1[1]); pk2.z = f2b(v1[2]); pk2.w = f2b(v1[3]);
            *(ushort4*)(lds + AK_V + (((16 + l15) * 704 + t0 * 2) ^ vsw)) = pk2;
        }
    }
    __syncthreads();

    // ---- phase B: per 64-row chunk: Q-proj + online-softmax attention ----
    const float* maskn = mask + (size_t)n * NV * NV;

    #pragma unroll 1
    for (int mc = 0; mc < 6; ++mc) {
        int r0 = mc * 64 + wvv * 16;
        if (r0 >= 352) continue;              // no barriers below: divergence safe
        int t0 = r0 + l4 * 4;

        // Q projection for this wave's 16 rows -> q_buf (aliases p_s, wave-private)
        {
            int rr = min(r0 + l15, NV - 1);
            const float* xp = xn + (size_t)rr * NC + l4 * 8;   // per-lane k-chunk offset
            bf16x8 a0 = ldx8(xp), a1 = ldx8(xp + 32), a2 = ldx8(xp + 64);
            f32x4 q0 = {0.f,0.f,0.f,0.f}, q1 = {0.f,0.f,0.f,0.f};
            q0 = mfma16(a0, BFRAG(wqp,0,0), q0); q0 = mfma16(a1, BFRAG(wqp,0,1), q0); q0 = mfma16(a2, BFRAG(wqp,0,2), q0);
            q1 = mfma16(a0, BFRAG(wqp,1,0), q1); q1 = mfma16(a1, BFRAG(wqp,1,1), q1); q1 = mfma16(a2, BFRAG(wqp,1,2), q1);
            #pragma unroll
            for (int j = 0; j < 4; ++j) {
                int row = wvv * 16 + l4 * 4 + j;
                int sw = (row & 3) << 4;
                *(unsigned short*)(lds + AK_QP + ((row * 64 + l15 * 2) ^ sw)) = f2b(q0[j]);
                *(unsigned short*)(lds + AK_QP + ((row * 64 + 32 + l15 * 2) ^ sw)) = f2b(q1[j]);
            }
        }
        asm volatile("s_waitcnt lgkmcnt(0)" ::: "memory");
        __builtin_amdgcn_sched_barrier(0);
        const int qrow = wvv * 16 + l15;
        const int paaddr = AK_QP + ((qrow * 64 + l4 * 16) ^ ((qrow & 3) << 4));
        bf16x8 qa = *(const bf16x8*)(lds + paaddr);

        float m0 = -1e30f, m1 = -1e30f, m2 = -1e30f, m3 = -1e30f;
        float L0 = 0.f, L1 = 0.f, L2 = 0.f, L3 = 0.f;
        f32x4 o0 = {0.f,0.f,0.f,0.f}, o1 = {0.f,0.f,0.f,0.f};
        int mv0 = (int)mcode[min(t0 + 0, NV - 1)] + 1098;
        int mv1 = (int)mcode[min(t0 + 1, NV - 1)] + 1098;
        int mv2 = (int)mcode[min(t0 + 2, NV - 1)] + 1098;
        int mv3 = (int)mcode[min(t0 + 3, NV - 1)] + 1098;
        const float* mrow0 = maskn + (size_t)min(t0 + 0, NV - 1) * NV;
        const float* mrow1 = maskn + (size_t)min(t0 + 1, NV - 1) * NV;
        const float* mrow2 = maskn + (size_t)min(t0 + 2, NV - 1) * NV;
        const float* mrow3 = maskn + (size_t)min(t0 + 3, NV - 1) * NV;

        #pragma unroll
        for (int tt = 0; tt < 11; ++tt) {
            const int u0 = tt * 32 + l15;                       // always < 343
            const int u1i = tt * 32 + 16 + l15;
            const int u1 = (tt == 10) ? min(u1i, NV - 1) : u1i; // clamp only last step
            // mask loads (L2/L3-resident after first block per window)
            float mk00 = mrow0[u0], mk01 = mrow1[u0], mk02 = mrow2[u0], mk03 = mrow3[u0];
            float mk10 = mrow0[u1], mk11 = mrow1[u1], mk12 = mrow2[u1], mk13 = mrow3[u1];
            // K fragments (swizzled LDS)
            int krow0 = tt * 32 + l15;
            bf16x8 kb0 = *(const bf16x8*)(lds + AK_K + ((krow0 * 64 + l4 * 16) ^ ((krow0 & 3) << 4)));
            int krow1 = krow0 + 16;
            bf16x8 kb1 = *(const bf16x8*)(lds + AK_K + ((krow1 * 64 + l4 * 16) ^ ((krow1 & 3) << 4)));
            f32x4 z = {0.f,0.f,0.f,0.f};
            f32x4 p0 = mfma16(qa, kb0, z);
            f32x4 p1 = mfma16(qa, kb1, z);
            int mu0 = (int)mcode[u0];
            int mu1 = (int)mcode[u1];
            float v00 = p0[0] + b2f(bias_l[mv0 - mu0]) + mk00;
            float v01 = p0[1] + b2f(bias_l[mv1 - mu0]) + mk01;
            float v02 = p0[2] + b2f(bias_l[mv2 - mu0]) + mk02;
            float v03 = p0[3] + b2f(bias_l[mv3 - mu0]) + mk03;
            float v10 = p1[0] + b2f(bias_l[mv0 - mu1]) + mk10;
            float v11 = p1[1] + b2f(bias_l[mv1 - mu1]) + mk11;
            float v12 = p1[2] + b2f(bias_l[mv2 - mu1]) + mk12;
            float v13 = p1[3] + b2f(bias_l[mv3 - mu1]) + mk13;
            if (tt == 10) {                      // u1i in [336,351]; valid iff < 343
                bool ok = (l15 < 7);
                v10 = ok ? v10 : -1e30f; v11 = ok ? v11 : -1e30f;
                v12 = ok ? v12 : -1e30f; v13 = ok ? v13 : -1e30f;
            }
            float pm0 = fmaxf(v00, v10), pm1 = fmaxf(v01, v11);
            float pm2 = fmaxf(v02, v12), pm3 = fmaxf(v03, v13);
            #pragma unroll
            for (int mm = 1; mm < 16; mm <<= 1) {
                pm0 = fmaxf(pm0, __shfl_xor(pm0, mm, 64));
                pm1 = fmaxf(pm1, __shfl_xor(pm1, mm, 64));
                pm2 = fmaxf(pm2, __shfl_xor(pm2, mm, 64));
                pm3 = fmaxf(pm3, __shfl_xor(pm3, mm, 64));
            }
            // defer-max (T13): rescale only when max grew by > 8
            float dmax = fmaxf(fmaxf(pm0 - m0, pm1 - m1), fmaxf(pm2 - m2, pm3 - m3));
            if (__any(dmax > 8.0f)) {
                float mn, sc;
                mn = fmaxf(m0, pm0); sc = __expf(m0 - mn); L0 *= sc; o0[0] *= sc; o1[0] *= sc; m0 = mn;
                mn = fmaxf(m1, pm1); sc = __expf(m1 - mn); L1 *= sc; o0[1] *= sc; o1[1] *= sc; m1 = mn;
                mn = fmaxf(m2, pm2); sc = __expf(m2 - mn); L2 *= sc; o0[2] *= sc; o1[2] *= sc; m2 = mn;
                mn = fmaxf(m3, pm3); sc = __expf(m3 - mn); L3 *= sc; o0[3] *= sc; o1[3] *= sc; m3 = mn;
            }
            float e00 = __expf(v00 - m0), e01 = __expf(v01 - m1);
            float e02 = __expf(v02 - m2), e03 = __expf(v03 - m3);
            float e10 = __expf(v10 - m0), e11 = __expf(v11 - m1);
            float e12 = __expf(v12 - m2), e13 = __expf(v13 - m3);
            L0 += e00 + e10; L1 += e01 + e11; L2 += e02 + e12; L3 += e03 + e13;
            // store e -> p_s (C-layout, swizzled, wave-private rows)
            {
                int pr = wvv * 16 + l4 * 4;
                int sw0 = ((pr + 0) & 3) << 4, sw1 = ((pr + 1) & 3) << 4;
                int sw2 = ((pr + 2) & 3) << 4, sw3 = ((pr + 3) & 3) << 4;
                *(unsigned short*)(lds + AK_QP + (((pr + 0) * 64 + l15 * 2) ^ sw0)) = f2b(e00);
                *(unsigned short*)(lds + AK_QP + (((pr + 1) * 64 + l15 * 2) ^ sw1)) = f2b(e01);
                *(unsigned short*)(lds + AK_QP + (((pr + 2) * 64 + l15 * 2) ^ sw2)) = f2b(e02);
                *(unsigned short*)(lds + AK_QP + (((pr + 3) * 64 + l15 * 2) ^ sw3)) = f2b(e03);
                *(unsigned short*)(lds + AK_QP + (((pr + 0) * 64 + 32 + l15 * 2) ^ sw0)) = f2b(e10);
                *(unsigned short*)(lds + AK_QP + (((pr + 1) * 64 + 32 + l15 * 2) ^ sw1)) = f2b(e11);
                *(unsigned short*)(lds + AK_QP + (((pr + 2) * 64 + 32 + l15 * 2) ^ sw2)) = f2b(e12);
                *(unsigned short*)(lds + AK_QP + (((pr + 3) * 64 + 32 + l15 * 2) ^ sw3)) = f2b(e13);
            }
            // V fragments (independent of p_s stores)
            int vt0 = (tt * 32 + l4 * 8) * 2;
            int vswA = (l15 & 3) << 4;
            bf16x8 vb0 = *(const bf16x8*)(lds + AK_V + ((l15 * 704 + vt0) ^ vswA));
            bf16x8 vb1 = *(const bf16x8*)(lds + AK_V + (((16 + l15) * 704 + vt0) ^ vswA));
            asm volatile("s_waitcnt lgkmcnt(0)" ::: "memory");   // p_s stores visible (G18)
            __builtin_amdgcn_sched_barrier(0);
            bf16x8 pa = *(const bf16x8*)(lds + paaddr);
            o0 = mfma16(pa, vb0, o0);
            o1 = mfma16(pa, vb1, o1);
        }

        #pragma unroll
        for (int mm = 1; mm < 16; mm <<= 1) {
            L0 += __shfl_xor(L0, mm, 64);
            L1 += __shfl_xor(L1, mm, 64);
            L2 += __shfl_xor(L2, mm, 64);
            L3 += __shfl_xor(L3, mm, 64);
        }
        float Ls[4] = {L0, L1, L2, L3};
        #pragma unroll
        for (int j = 0; j < 4; ++j) {
            int tok = t0 + j;
            if (tok < NV) {
                float inv = 1.0f / Ls[j];
                float* op = out + ((size_t)n * NV + tok) * NC + h * 32;
                op[l15] = o0[j] * inv;
                op[16 + l15] = o1[j] * inv;
            }
        }
    }
#undef BFRAG
}

// ======================= fallback: proven fused kernel (r3, 237us) =========
#define OFF_Q    0
#define OFF_K    22528
#define OFF_VT   45056
#define OFF_BIAS 67584
#define OFF_MC   76384
#define OFF_U    77760
#define OFF_XS   OFF_U
#define OFF_WS   (OFF_U + 13312)
#define OFF_PS   OFF_U
#define LDS_BYTES (OFF_U + 45056)
#define VPAD 352

__global__ __launch_bounds__(256) void wattn(
    const float* __restrict__ x, const float* __restrict__ mask,
    const float* __restrict__ w_qkv, const float* __restrict__ bias_table,
    const int* __restrict__ rel_index, float* __restrict__ out)
{
    extern __shared__ char flds[];
    unsigned short* q_s  = (unsigned short*)(flds + OFF_Q);
    unsigned short* k_s  = (unsigned short*)(flds + OFF_K);
    unsigned short* v_t  = (unsigned short*)(flds + OFF_VT);
    float*          bias_l = (float*)(flds + OFF_BIAS);
    int*            mcode  = (int*)(flds + OFF_MC);
    unsigned short* xs   = (unsigned short*)(flds + OFF_XS);
    unsigned short* ws   = (unsigned short*)(flds + OFF_WS);
    unsigned short* p_s  = (unsigned short*)(flds + OFF_PS);

    const int tid = threadIdx.x;
    const int lane = tid & 63;
    const int wv  = tid >> 6;
    const int l15 = lane & 15;
    const int l4  = lane >> 4;

    int bid = blockIdx.x;
    int linear = (bid & 7) * 96 + (bid >> 3);
    int n = linear / 3;
    int h = linear - n * 3;

    for (int i = tid; i < NTABLE; i += 256) bias_l[i] = bias_table[h * NTABLE + i];
    for (int i = tid; i < NV; i += 256) {
        int cz = i / 49; int rr = i - cz * 49; int cy = rr / 7; int cx = rr - cy * 7;
        mcode[i] = cz * 169 + cy * 13 + cx;
    }
    for (int i = tid; i < 96 * 24; i += 256) {
        int nr = i / 24, c4 = i - nr * 24;
        int g = nr >> 5, d = nr & 31;
        const float4 wq = *(const float4*)(w_qkv + (size_t)(g * NC + h * 32 + d) * NC + c4 * 4);
        float s = (g == 0) ? SCALE_Q : 1.0f;
        unsigned short* dst = ws + nr * 104 + c4 * 4;
        dst[0] = f2b(wq.x * s); dst[1] = f2b(wq.y * s);
        dst[2] = f2b(wq.z * s); dst[3] = f2b(wq.w * s);
    }
    for (int mc = 0; mc < 6; ++mc) {
        __syncthreads();
        for (int i = tid; i < 64 * 24; i += 256) {
            int r = i / 24, c4 = i - r * 24;
            int tok = mc * 64 + r;
            float4 xv = make_float4(0.f, 0.f, 0.f, 0.f);
            if (tok < NV) xv = *(const float4*)(x + ((size_t)n * NV + tok) * NC + c4 * 4);
            unsigned short* dst = xs + r * 104 + c4 * 4;
            dst[0] = f2b(xv.x); dst[1] = f2b(xv.y); dst[2] = f2b(xv.z); dst[3] = f2b(xv.w);
        }
        __syncthreads();
        int r0 = mc * 64 + wv * 16;
        if (r0 < VPAD) {
            bf16x8 a[3];
            #pragma unroll
            for (int ks = 0; ks < 3; ++ks)
                a[ks] = *(const bf16x8*)(xs + (wv * 16 + l15) * 104 + ks * 32 + l4 * 8);
            #pragma unroll
            for (int nt = 0; nt < 6; ++nt) {
                f32x4 acc = {0.f, 0.f, 0.f, 0.f};
                #pragma unroll
                for (int ks = 0; ks < 3; ++ks) {
                    bf16x8 b = *(const bf16x8*)(ws + (nt * 16 + l15) * 104 + ks * 32 + l4 * 8);
                    acc = mfma16(a[ks], b, acc);
                }
                int ch = (nt & 1) * 16 + l15;
                int t0 = r0 + l4 * 4;
                if (nt < 2) {
                    #pragma unroll
                    for (int j = 0; j < 4; ++j) q_s[(t0 + j) * 32 + ch] = f2b(acc[j]);
                } else if (nt < 4) {
                    #pragma unroll
                    for (int j = 0; j < 4; ++j) k_s[(t0 + j) * 32 + ch] = f2b(acc[j]);
                } else {
                    ushort4 pk;
                    pk.x = f2b(acc[0]); pk.y = f2b(acc[1]);
                    pk.z = f2b(acc[2]); pk.w = f2b(acc[3]);
                    *(ushort4*)(v_t + ch * VPAD + t0) = pk;
                }
            }
        }
    }
    __syncthreads();

    const float* maskn = mask + (size_t)n * NV * NV;
    for (int mc = 0; mc < 6; ++mc) {
        int r0 = mc * 64 + wv * 16;
        if (r0 >= VPAD) continue;
        int t0 = r0 + l4 * 4;
        float mk[22][4];
        #pragma unroll
        for (int t = 0; t < 22; ++t) {
            int u = t * 16 + l15;
            #pragma unroll
            for (int j = 0; j < 4; ++j) {
                int tok = t0 + j;
                mk[t][j] = (u < NV && tok < NV) ? maskn[(size_t)tok * NV + u] : 0.f;
            }
        }
        bf16x8 qa = *(const bf16x8*)(q_s + (r0 + l15) * 32 + l4 * 8);
        f32x4 p[22];
        #pragma unroll
        for (int t = 0; t < 22; ++t) {
            bf16x8 kb = *(const bf16x8*)(k_s + (t * 16 + l15) * 32 + l4 * 8);
            f32x4 z = {0.f, 0.f, 0.f, 0.f};
            p[t] = mfma16(qa, kb, z);
        }
        int mv[4];
        #pragma unroll
        for (int j = 0; j < 4; ++j) {
            int tok = t0 + j;
            mv[j] = mcode[tok < NV ? tok : 0] + 1098;
        }
        float rmax[4] = {-1e30f, -1e30f, -1e30f, -1e30f};
        #pragma unroll
        for (int t = 0; t < 22; ++t) {
            int u = t * 16 + l15;
            bool uv = (u < NV);
            int mu = mcode[uv ? u : 0];
            #pragma unroll
            for (int j = 0; j < 4; ++j) {
                float val = p[t][j] + bias_l[mv[j] - mu] + mk[t][j];
                val = uv ? val : -1e30f;
                p[t][j] = val;
                rmax[j] = fmaxf(rmax[j], val);
            }
        }
        #pragma unroll
        for (int m = 1; m < 16; m <<= 1) {
            #pragma unroll
            for (int j = 0; j < 4; ++j)
                rmax[j] = fmaxf(rmax[j], __shfl_xor(rmax[j], m, 64));
        }
        float rsum[4] = {0.f, 0.f, 0.f, 0.f};
        #pragma unroll
        for (int t = 0; t < 22; ++t) {
            #pragma unroll
            for (int j = 0; j < 4; ++j) {
                float e = __expf(p[t][j] - rmax[j]);
                rsum[j] += e;
                p_s[(wv * 16 + l4 * 4 + j) * VPAD + t * 16 + l15] = f2b(e);
            }
        }
        #pragma unroll
        for (int m = 1; m < 16; m <<= 1) {
            #pragma unroll
            for (int j = 0; j < 4; ++j)
                rsum[j] += __shfl_xor(rsum[j], m, 64);
        }
        f32x4 o0 = {0.f,0.f,0.f,0.f}, o1 = {0.f,0.f,0.f,0.f};
        #pragma unroll
        for (int ks = 0; ks < 11; ++ks) {
            bf16x8 pa  = *(const bf16x8*)(p_s + (wv * 16 + l15) * VPAD + ks * 32 + l4 * 8);
            bf16x8 vb0 = *(const bf16x8*)(v_t + l15 * VPAD + ks * 32 + l4 * 8);
            bf16x8 vb1 = *(const bf16x8*)(v_t + (16 + l15) * VPAD + ks * 32 + l4 * 8);
            o0 = mfma16(pa, vb0, o0);
            o1 = mfma16(pa, vb1, o1);
        }
        #pragma unroll
        for (int j = 0; j < 4; ++j) {
            int tok = t0 + j;
            if (tok < NV) {
                float inv = 1.0f / rsum[j];
                float* op = out + ((size_t)n * NV + tok) * NC + h * 32;
                op[l15]      = o0[j] * inv;
                op[16 + l15] = o1[j] * inv;
            }
        }
    }
}

extern "C" void kernel_launch(void* const* d_in, const int* in_sizes, int n_in,
                              void* d_out, int out_size, void* d_ws, size_t ws_size,
                              hipStream_t stream) {
    const float* x          = (const float*)d_in[0];
    const float* mask       = (const float*)d_in[1];
    const float* w_qkv      = (const float*)d_in[2];
    const float* bias_table = (const float*)d_in[3];
    const int*   rel_index  = (const int*)d_in[4];
    float* out = (float*)d_out;

    (void)rel_index; (void)in_sizes; (void)n_in; (void)out_size;

    if (ws_size >= WS_NEEDED) {
        unsigned short* wbf = (unsigned short*)d_ws;
        wcvt<<<dim3(108), dim3(256), 0, stream>>>(w_qkv, wbf);
        attn<<<dim3(NWIN * NH), dim3(256), 0, stream>>>(x, mask, wbf, bias_table, out);
    } else {
        hipFuncSetAttribute((const void*)wattn, hipFuncAttributeMaxDynamicSharedMemorySize, LDS_BYTES);
        wattn<<<dim3(NWIN * NH), dim3(256), LDS_BYTES, stream>>>(x, mask, w_qkv, bias_table, rel_index, out);
    }
}

// Round 8
// 287.548 us; speedup vs baseline: 1.7471x; 1.1995x over previous
//
#include <hip/hip_runtime.h>
#include <hip/hip_bf16.h>

#define NWIN 256
#define NV 343
#define NC 96
#define NH 3
#define NTABLE 2197
#define SCALE_Q 0.17677669529663687f
#define LOG2E 1.4426950408889634f

typedef __attribute__((ext_vector_type(8))) short bf16x8;
typedef __attribute__((ext_vector_type(4))) float f32x4;

static __device__ __forceinline__ unsigned short f2b(float f) {
    union { __hip_bfloat16 b; unsigned short u; } cv;
    cv.b = __float2bfloat16(f);
    return cv.u;
}
static __device__ __forceinline__ float b2f(unsigned short u) {
    union { unsigned short u; __hip_bfloat16 b; } cv;
    cv.u = u;
    return __bfloat162float(cv.b);
}
static __device__ __forceinline__ f32x4 mfma16(bf16x8 a, bf16x8 b, f32x4 c) {
    return __builtin_amdgcn_mfma_f32_16x16x32_bf16(a, b, c, 0, 0, 0);
}
static __device__ __forceinline__ bf16x8 ldx8(const float* p) {
    float4 x0 = *(const float4*)p;
    float4 x1 = *(const float4*)(p + 4);
    bf16x8 t;
    t[0] = (short)f2b(x0.x); t[1] = (short)f2b(x0.y);
    t[2] = (short)f2b(x0.z); t[3] = (short)f2b(x0.w);
    t[4] = (short)f2b(x1.x); t[5] = (short)f2b(x1.y);
    t[6] = (short)f2b(x1.z); t[7] = (short)f2b(x1.w);
    return t;
}

// ======================= workspace =======================
#define WS_NEEDED (288 * 96 * 2)

// W -> bf16; Q rows get SCALE * LOG2E folded in (exp2-domain softmax)
__global__ __launch_bounds__(256) void wcvt(const float* __restrict__ w,
                                            unsigned short* __restrict__ wbf) {
    int i = blockIdx.x * 256 + threadIdx.x;   // 288*96 = 27648 exact
    float v = w[i];
    if (i < 96 * 96) v *= SCALE_Q * LOG2E;
    wbf[i] = f2b(v);
}

// ======================= fused attention, swapped-QK^T =======================
// LDS: k_s [352][32] bf16 swz | v_t [32][352] bf16 swz, COLUMN-PERMUTED per
//      32-token block (s = quad*8 + (r>=16?4:0) + (r&3)) so PV's A-frag k-slots
//      match the e-values each lane holds after S^T | bias bf16 (x LOG2E) |
//      mcode i16 [352] (padded) | q_buf [64][32] bf16 swz
// Swizzle: byte ^ ((row&3)<<4) — bits 4-5, in-row bijective.
#define AK_K   0
#define AK_V   22528
#define AK_B   45056
#define AK_MC  49456
#define AK_QP  50160
#define AK_LDS 54256   // x3 = 162768 <= 163840

__global__ __launch_bounds__(256, 3) void attn(
    const float* __restrict__ x, const float* __restrict__ mask,
    const unsigned short* __restrict__ wbf, const float* __restrict__ bias_table,
    float* __restrict__ out)
{
    __shared__ char lds[AK_LDS];
    unsigned short* bias_l = (unsigned short*)(lds + AK_B);
    short* mcode = (short*)(lds + AK_MC);

    const int tid = threadIdx.x;
    const int lane = tid & 63;
    const int wvv = tid >> 6;
    const int l15 = lane & 15;
    const int l4 = lane >> 4;

    int bid = blockIdx.x;
    int linear = (bid & 7) * 96 + (bid >> 3);   // 3 heads of a window -> same XCD
    int n = linear / 3;
    int h = linear - n * 3;

    for (int i = tid; i < NTABLE; i += 256)
        bias_l[i] = f2b(bias_table[h * NTABLE + i] * LOG2E);
    for (int i = tid; i < 352; i += 256) {
        int t = min(i, NV - 1);
        int cz = t / 49; int rr = t - cz * 49; int cy = rr / 7; int cx = rr - cy * 7;
        mcode[i] = (short)(cz * 169 + cy * 13 + cx);  // rel_index(v,u)==mcode[v]-mcode[u]+1098
    }

    const unsigned short* wqp = wbf + (h * 32) * NC;
    const unsigned short* wkp = wbf + (96 + h * 32) * NC;
    const unsigned short* wvp = wbf + (192 + h * 32) * NC;
    const float* xn = x + (size_t)n * NV * NC;

#define BFRAG(WP, T, KS) (*(const bf16x8*)((WP) + ((T) * 16 + l15) * NC + (KS) * 32 + l4 * 8))

    // ---- phase A: K,V projection; V stored transposed + column-permuted ----
    #pragma unroll 1
    for (int mc = 0; mc < 6; ++mc) {
        int r0 = mc * 64 + wvv * 16;
        if (r0 >= 352) continue;
        int rr = min(r0 + l15, NV - 1);
        const float* xp = xn + (size_t)rr * NC + l4 * 8;
        bf16x8 a0 = ldx8(xp), a1 = ldx8(xp + 32), a2 = ldx8(xp + 64);
        f32x4 k0 = {0.f,0.f,0.f,0.f}, k1 = {0.f,0.f,0.f,0.f};
        f32x4 v0 = {0.f,0.f,0.f,0.f}, v1 = {0.f,0.f,0.f,0.f};
        k0 = mfma16(a0, BFRAG(wkp,0,0), k0); k0 = mfma16(a1, BFRAG(wkp,0,1), k0); k0 = mfma16(a2, BFRAG(wkp,0,2), k0);
        k1 = mfma16(a0, BFRAG(wkp,1,0), k1); k1 = mfma16(a1, BFRAG(wkp,1,1), k1); k1 = mfma16(a2, BFRAG(wkp,1,2), k1);
        v0 = mfma16(a0, BFRAG(wvp,0,0), v0); v0 = mfma16(a1, BFRAG(wvp,0,1), v0); v0 = mfma16(a2, BFRAG(wvp,0,2), v0);
        v1 = mfma16(a0, BFRAG(wvp,1,0), v1); v1 = mfma16(a1, BFRAG(wvp,1,1), v1); v1 = mfma16(a2, BFRAG(wvp,1,2), v1);
        int t0 = r0 + l4 * 4;
        #pragma unroll
        for (int j = 0; j < 4; ++j) {
            int row = t0 + j;
            int sw = (row & 3) << 4;
            *(unsigned short*)(lds + AK_K + ((row * 64 + l15 * 2) ^ sw)) = f2b(k0[j]);
            *(unsigned short*)(lds + AK_K + ((row * 64 + 32 + l15 * 2) ^ sw)) = f2b(k1[j]);
        }
        {
            int rb = t0 & 31;          // (wvv&1)*16 + l4*4
            int sbase = (rb < 16) ? ((rb >> 2) * 8) : ((((rb - 16) >> 2) * 8) + 4);
            int colb = ((t0 >> 5) * 32 + sbase) * 2;   // permuted byte col
            int vsw = (l15 & 3) << 4;
            ushort4 pk;
            pk.x = f2b(v0[0]); pk.y = f2b(v0[1]); pk.z = f2b(v0[2]); pk.w = f2b(v0[3]);
            *(ushort4*)(lds + AK_V + ((l15 * 704 + colb) ^ vsw)) = pk;
            ushort4 pk2;
            pk2.x = f2b(v1[0]); pk2.y = f2b(v1[1]); pk2.z = f2b(v1[2]); pk2.w = f2b(v1[3]);
            *(ushort4*)(lds + AK_V + (((16 + l15) * 704 + colb) ^ vsw)) = pk2;
        }
    }
    __syncthreads();

    // ---- phase B: per 64-row chunk: Q-proj + exp2-domain softmax (no max) ----
    const float* maskn = mask + (size_t)n * NV * NV;

    #pragma unroll 1
    for (int mc = 0; mc < 6; ++mc) {
        int r0 = mc * 64 + wvv * 16;
        if (r0 >= 352) continue;              // no barriers below: divergence safe
        int t0 = r0 + l4 * 4;

        // Q projection for this wave's 16 rows -> q_buf (wave-private)
        {
            int rr = min(r0 + l15, NV - 1);
            const float* xp = xn + (size_t)rr * NC + l4 * 8;
            bf16x8 a0 = ldx8(xp), a1 = ldx8(xp + 32), a2 = ldx8(xp + 64);
            f32x4 q0 = {0.f,0.f,0.f,0.f}, q1 = {0.f,0.f,0.f,0.f};
            q0 = mfma16(a0, BFRAG(wqp,0,0), q0); q0 = mfma16(a1, BFRAG(wqp,0,1), q0); q0 = mfma16(a2, BFRAG(wqp,0,2), q0);
            q1 = mfma16(a0, BFRAG(wqp,1,0), q1); q1 = mfma16(a1, BFRAG(wqp,1,1), q1); q1 = mfma16(a2, BFRAG(wqp,1,2), q1);
            #pragma unroll
            for (int j = 0; j < 4; ++j) {
                int row = wvv * 16 + l4 * 4 + j;
                int sw = (row & 3) << 4;
                *(unsigned short*)(lds + AK_QP + ((row * 64 + l15 * 2) ^ sw)) = f2b(q0[j]);
                *(unsigned short*)(lds + AK_QP + ((row * 64 + 32 + l15 * 2) ^ sw)) = f2b(q1[j]);
            }
        }
        asm volatile("s_waitcnt lgkmcnt(0)" ::: "memory");
        __builtin_amdgcn_sched_barrier(0);
        const int qrow = wvv * 16 + l15;
        bf16x8 qa = *(const bf16x8*)(lds + AK_QP + ((qrow * 64 + l4 * 16) ^ ((qrow & 3) << 4)));

        const int qr = min(r0 + l15, NV - 1);               // this lane's q-row
        const float* mrow = maskn + (size_t)qr * NV;
        const int mvq = (int)mcode[qr] + 1098;

        float L = 0.f;
        f32x4 o0 = {0.f,0.f,0.f,0.f}, o1 = {0.f,0.f,0.f,0.f};

        // mask prefetch regs: current + next
        float mkc[8], mkn[8];
        #pragma unroll
        for (int j = 0; j < 4; ++j) {
            mkc[j]     = mrow[l4 * 4 + j];
            mkc[4 + j] = mrow[16 + l4 * 4 + j];
        }

        #pragma unroll
        for (int tt = 0; tt < 11; ++tt) {
            // K fragments (swizzled LDS), S^T = mfma(K, Q)
            int krow0 = tt * 32 + l15;
            bf16x8 kb0 = *(const bf16x8*)(lds + AK_K + ((krow0 * 64 + l4 * 16) ^ ((krow0 & 3) << 4)));
            int krow1 = krow0 + 16;
            bf16x8 kb1 = *(const bf16x8*)(lds + AK_K + ((krow1 * 64 + l4 * 16) ^ ((krow1 & 3) << 4)));
            f32x4 z = {0.f,0.f,0.f,0.f};
            f32x4 st0 = mfma16(kb0, qa, z);   // lane: u = tt*32 + l4*4+j, qrow = l15
            f32x4 st1 = mfma16(kb1, qa, z);   // lane: u = tt*32+16 + l4*4+j

            // prefetch next tile's mask (u consecutive per lane)
            if (tt < 10) {
                int ub = (tt + 1) * 32 + l4 * 4;
                #pragma unroll
                for (int j = 0; j < 4; ++j) {
                    mkn[j]     = mrow[ub + j];
                    mkn[4 + j] = mrow[min(ub + 16 + j, NV - 1)];
                }
            }

            // mcode for this tile's u's (vector LDS reads)
            short4 mcA = *(const short4*)(mcode + tt * 32 + l4 * 4);
            short4 mcB = *(const short4*)(mcode + tt * 32 + 16 + l4 * 4);
            int muA[4] = {mcA.x, mcA.y, mcA.z, mcA.w};
            int muB[4] = {mcB.x, mcB.y, mcB.z, mcB.w};

            float e[8];
            #pragma unroll
            for (int j = 0; j < 4; ++j) {
                float vA = st0[j] + b2f(bias_l[mvq - muA[j]]) + mkc[j] * LOG2E;
                e[j] = exp2f(vA);
                float vB = st1[j] + b2f(bias_l[mvq - muB[j]]) + mkc[4 + j] * LOG2E;
                if (tt == 10) vB = (l4 * 4 + j < 7) ? vB : -1e30f;
                e[4 + j] = exp2f(vB);
            }
            L += ((e[0] + e[1]) + (e[2] + e[3])) + ((e[4] + e[5]) + (e[6] + e[7]));

            // pack P A-fragment: [st0 j0..3 | st1 j0..3] matches permuted V k-slots
            bf16x8 pa;
            #pragma unroll
            for (int i = 0; i < 8; ++i) pa[i] = (short)f2b(e[i]);

            int vcol = (tt * 32 + l4 * 8) * 2;
            int vsw = (l15 & 3) << 4;
            bf16x8 vb0 = *(const bf16x8*)(lds + AK_V + ((l15 * 704 + vcol) ^ vsw));
            bf16x8 vb1 = *(const bf16x8*)(lds + AK_V + (((16 + l15) * 704 + vcol) ^ vsw));
            o0 = mfma16(pa, vb0, o0);   // C: row = l4*4+j (q-row), col = l15 (ch)
            o1 = mfma16(pa, vb1, o1);

            #pragma unroll
            for (int i = 0; i < 8; ++i) mkc[i] = mkn[i];
        }

        // L reduce across l4 groups (row = l15 holds partial)
        L += __shfl_xor(L, 16, 64);
        L += __shfl_xor(L, 32, 64);

        #pragma unroll
        for (int j = 0; j < 4; ++j) {
            float Lr = __shfl(L, l4 * 4 + j, 64);   // L for row l4*4+j
            int tok = t0 + j;
            if (tok < NV) {
                float inv = 1.0f / Lr;
                float* op = out + ((size_t)n * NV + tok) * NC + h * 32;
                op[l15]      = o0[j] * inv;
                op[16 + l15] = o1[j] * inv;
            }
        }
    }
#undef BFRAG
}

// ======================= fallback: proven fused kernel (r3, 237us) =========
#define OFF_Q    0
#define OFF_K    22528
#define OFF_VT   45056
#define OFF_BIAS 67584
#define OFF_MC   76384
#define OFF_U    77760
#define OFF_XS   OFF_U
#define OFF_WS   (OFF_U + 13312)
#define OFF_PS   OFF_U
#define LDS_BYTES (OFF_U + 45056)
#define VPAD 352

__global__ __launch_bounds__(256) void wattn(
    const float* __restrict__ x, const float* __restrict__ mask,
    const float* __restrict__ w_qkv, const float* __restrict__ bias_table,
    const int* __restrict__ rel_index, float* __restrict__ out)
{
    extern __shared__ char flds[];
    unsigned short* q_s  = (unsigned short*)(flds + OFF_Q);
    unsigned short* k_s  = (unsigned short*)(flds + OFF_K);
    unsigned short* v_t  = (unsigned short*)(flds + OFF_VT);
    float*          bias_l = (float*)(flds + OFF_BIAS);
    int*            mcode  = (int*)(flds + OFF_MC);
    unsigned short* xs   = (unsigned short*)(flds + OFF_XS);
    unsigned short* ws   = (unsigned short*)(flds + OFF_WS);
    unsigned short* p_s  = (unsigned short*)(flds + OFF_PS);

    const int tid = threadIdx.x;
    const int lane = tid & 63;
    const int wv  = tid >> 6;
    const int l15 = lane & 15;
    const int l4  = lane >> 4;

    int bid = blockIdx.x;
    int linear = (bid & 7) * 96 + (bid >> 3);
    int n = linear / 3;
    int h = linear - n * 3;

    for (int i = tid; i < NTABLE; i += 256) bias_l[i] = bias_table[h * NTABLE + i];
    for (int i = tid; i < NV; i += 256) {
        int cz = i / 49; int rr = i - cz * 49; int cy = rr / 7; int cx = rr - cy * 7;
        mcode[i] = cz * 169 + cy * 13 + cx;
    }
    for (int i = tid; i < 96 * 24; i += 256) {
        int nr = i / 24, c4 = i - nr * 24;
        int g = nr >> 5, d = nr & 31;
        const float4 wq = *(const float4*)(w_qkv + (size_t)(g * NC + h * 32 + d) * NC + c4 * 4);
        float s = (g == 0) ? SCALE_Q : 1.0f;
        unsigned short* dst = ws + nr * 104 + c4 * 4;
        dst[0] = f2b(wq.x * s); dst[1] = f2b(wq.y * s);
        dst[2] = f2b(wq.z * s); dst[3] = f2b(wq.w * s);
    }
    for (int mc = 0; mc < 6; ++mc) {
        __syncthreads();
        for (int i = tid; i < 64 * 24; i += 256) {
            int r = i / 24, c4 = i - r * 24;
            int tok = mc * 64 + r;
            float4 xv = make_float4(0.f, 0.f, 0.f, 0.f);
            if (tok < NV) xv = *(const float4*)(x + ((size_t)n * NV + tok) * NC + c4 * 4);
            unsigned short* dst = xs + r * 104 + c4 * 4;
            dst[0] = f2b(xv.x); dst[1] = f2b(xv.y); dst[2] = f2b(xv.z); dst[3] = f2b(xv.w);
        }
        __syncthreads();
        int r0 = mc * 64 + wv * 16;
        if (r0 < VPAD) {
            bf16x8 a[3];
            #pragma unroll
            for (int ks = 0; ks < 3; ++ks)
                a[ks] = *(const bf16x8*)(xs + (wv * 16 + l15) * 104 + ks * 32 + l4 * 8);
            #pragma unroll
            for (int nt = 0; nt < 6; ++nt) {
                f32x4 acc = {0.f, 0.f, 0.f, 0.f};
                #pragma unroll
                for (int ks = 0; ks < 3; ++ks) {
                    bf16x8 b = *(const bf16x8*)(ws + (nt * 16 + l15) * 104 + ks * 32 + l4 * 8);
                    acc = mfma16(a[ks], b, acc);
                }
                int ch = (nt & 1) * 16 + l15;
                int t0 = r0 + l4 * 4;
                if (nt < 2) {
                    #pragma unroll
                    for (int j = 0; j < 4; ++j) q_s[(t0 + j) * 32 + ch] = f2b(acc[j]);
                } else if (nt < 4) {
                    #pragma unroll
                    for (int j = 0; j < 4; ++j) k_s[(t0 + j) * 32 + ch] = f2b(acc[j]);
                } else {
                    ushort4 pk;
                    pk.x = f2b(acc[0]); pk.y = f2b(acc[1]);
                    pk.z = f2b(acc[2]); pk.w = f2b(acc[3]);
                    *(ushort4*)(v_t + ch * VPAD + t0) = pk;
                }
            }
        }
    }
    __syncthreads();

    const float* maskn = mask + (size_t)n * NV * NV;
    for (int mc = 0; mc < 6; ++mc) {
        int r0 = mc * 64 + wv * 16;
        if (r0 >= VPAD) continue;
        int t0 = r0 + l4 * 4;
        float mk[22][4];
        #pragma unroll
        for (int t = 0; t < 22; ++t) {
            int u = t * 16 + l15;
            #pragma unroll
            for (int j = 0; j < 4; ++j) {
                int tok = t0 + j;
                mk[t][j] = (u < NV && tok < NV) ? maskn[(size_t)tok * NV + u] : 0.f;
            }
        }
        bf16x8 qa = *(const bf16x8*)(q_s + (r0 + l15) * 32 + l4 * 8);
        f32x4 p[22];
        #pragma unroll
        for (int t = 0; t < 22; ++t) {
            bf16x8 kb = *(const bf16x8*)(k_s + (t * 16 + l15) * 32 + l4 * 8);
            f32x4 z = {0.f, 0.f, 0.f, 0.f};
            p[t] = mfma16(qa, kb, z);
        }
        int mv[4];
        #pragma unroll
        for (int j = 0; j < 4; ++j) {
            int tok = t0 + j;
            mv[j] = mcode[tok < NV ? tok : 0] + 1098;
        }
        float rmax[4] = {-1e30f, -1e30f, -1e30f, -1e30f};
        #pragma unroll
        for (int t = 0; t < 22; ++t) {
            int u = t * 16 + l15;
            bool uv = (u < NV);
            int mu = mcode[uv ? u : 0];
            #pragma unroll
            for (int j = 0; j < 4; ++j) {
                float val = p[t][j] + bias_l[mv[j] - mu] + mk[t][j];
                val = uv ? val : -1e30f;
                p[t][j] = val;
                rmax[j] = fmaxf(rmax[j], val);
            }
        }
        #pragma unroll
        for (int m = 1; m < 16; m <<= 1) {
            #pragma unroll
            for (int j = 0; j < 4; ++j)
                rmax[j] = fmaxf(rmax[j], __shfl_xor(rmax[j], m, 64));
        }
        float rsum[4] = {0.f, 0.f, 0.f, 0.f};
        #pragma unroll
        for (int t = 0; t < 22; ++t) {
            #pragma unroll
            for (int j = 0; j < 4; ++j) {
                float e = __expf(p[t][j] - rmax[j]);
                rsum[j] += e;
                p_s[(wv * 16 + l4 * 4 + j) * VPAD + t * 16 + l15] = f2b(e);
            }
        }
        #pragma unroll
        for (int m = 1; m < 16; m <<= 1) {
            #pragma unroll
            for (int j = 0; j < 4; ++j)
                rsum[j] += __shfl_xor(rsum[j], m, 64);
        }
        f32x4 o0 = {0.f,0.f,0.f,0.f}, o1 = {0.f,0.f,0.f,0.f};
        #pragma unroll
        for (int ks = 0; ks < 11; ++ks) {
            bf16x8 pa  = *(const bf16x8*)(p_s + (wv * 16 + l15) * VPAD + ks * 32 + l4 * 8);
            bf16x8 vb0 = *(const bf16x8*)(v_t + l15 * VPAD + ks * 32 + l4 * 8);
            bf16x8 vb1 = *(const bf16x8*)(v_t + (16 + l15) * VPAD + ks * 32 + l4 * 8);
            o0 = mfma16(pa, vb0, o0);
            o1 = mfma16(pa, vb1, o1);
        }
        #pragma unroll
        for (int j = 0; j < 4; ++j) {
            int tok = t0 + j;
            if (tok < NV) {
                float inv = 1.0f / rsum[j];
                float* op = out + ((size_t)n * NV + tok) * NC + h * 32;
                op[l15]      = o0[j] * inv;
                op[16 + l15] = o1[j] * inv;
            }
        }
    }
}

extern "C" void kernel_launch(void* const* d_in, const int* in_sizes, int n_in,
                              void* d_out, int out_size, void* d_ws, size_t ws_size,
                              hipStream_t stream) {
    const float* x          = (const float*)d_in[0];
    const float* mask       = (const float*)d_in[1];
    const float* w_qkv      = (const float*)d_in[2];
    const float* bias_table = (const float*)d_in[3];
    const int*   rel_index  = (const int*)d_in[4];
    float* out = (float*)d_out;

    (void)rel_index; (void)in_sizes; (void)n_in; (void)out_size;

    if (ws_size >= WS_NEEDED) {
        unsigned short* wbf = (unsigned short*)d_ws;
        wcvt<<<dim3(108), dim3(256), 0, stream>>>(w_qkv, wbf);
        attn<<<dim3(NWIN * NH), dim3(256), 0, stream>>>(x, mask, wbf, bias_table, out);
    } else {
        hipFuncSetAttribute((const void*)wattn, hipFuncAttributeMaxDynamicSharedMemorySize, LDS_BYTES);
        wattn<<<dim3(NWIN * NH), dim3(256), LDS_BYTES, stream>>>(x, mask, w_qkv, bias_table, rel_index, out);
    }
}